// Round 1
// baseline (1854.555 us; speedup 1.0000x reference)
//
#include <hip/hip_runtime.h>

// Event histogram: N events (t,xs,ys,p) -> (4,2,2,256,300) fp32 histogram.
// t sorted ascending; p in {0,1}. All bin indices provably in range, so the
// reference's clip() is a no-op and the stacked output index decomposes as
//   out = dt*307200 + p*153600 + c*76800 + tok*300 + pos   (c=0 count, c=1 wt)

#define TOTAL_OUT 1228800

__global__ __launch_bounds__(256) void e2src_hist(const float4* __restrict__ x,
                                                  float* __restrict__ out,
                                                  int n) {
    // Broadcast scalars: t0 = x[0].t, tlast = x[n-1].t  (L1-cached after first hit)
    const float* xf = (const float*)x;
    const float t0    = xf[0];
    const float tlast = xf[(size_t)(n - 1) * 4];

    const float d_wt = tlast - t0 + 1e-4f;   // denom for wt  (B = 0.0001)
    const float d_dt = tlast - t0 + 1.0f;    // denom for dtime
    // Python-scalar constants, computed in double then narrowed to f32 (JAX behavior)
    const float c1 = (float)(319.0 / 20.0 + 1e-4);  // W/PW + B = 15.9501
    const float c2 = (float)(239.0 / 15.0 + 1e-4);  // H/PH + B = 15.93343...

    int i = blockIdx.x * blockDim.x + threadIdx.x;
    const int stride = gridDim.x * blockDim.x;
    for (; i < n; i += stride) {
        float4 e = x[i];                 // coalesced 16B/lane
        const float t  = e.x;
        const float xs = e.y;
        const float ys = e.z;
        const float p  = e.w;

        const float w  = (p != 2.0f) ? 1.0f : 0.0f;
        const float wt = (t - t0) / d_wt;                    // IEEE f32 divide

        // pos = floor(xs/c1) + floor(ys/c2)*PW
        const int pos = (int)(floorf(xs / c1) + floorf(ys / c2) * 20.0f);
        // tok = floor(xs % c1) + floor(ys % c2) * 16
        const int tok = (int)(floorf(fmodf(xs, c1)) + floorf(fmodf(ys, c2)) * 16.0f);
        // dtime = floor(4*(t-t0)/d_dt)  -- provably in [0,3]
        const int dt  = (int)floorf(4.0f * (t - t0) / d_dt);
        const int pp  = (int)p;

        const int base = dt * 307200 + pp * 153600 + tok * 300 + pos;
        unsafeAtomicAdd(out + base,         w);   // c=0: count
        unsafeAtomicAdd(out + base + 76800, wt);  // c=1: wt sum
    }
}

extern "C" void kernel_launch(void* const* d_in, const int* in_sizes, int n_in,
                              void* d_out, int out_size, void* d_ws, size_t ws_size,
                              hipStream_t stream) {
    const float* x = (const float*)d_in[0];
    float* out = (float*)d_out;
    const int n = in_sizes[0] / 4;   // events

    // Harness poisons d_out with 0xAA every call — zero it (graph-capture safe).
    hipMemsetAsync(d_out, 0, (size_t)out_size * sizeof(float), stream);

    const int threads = 256;
    const int blocks  = 8192;        // 2M threads, ~8 events each (grid-stride)
    hipLaunchKernelGGL(e2src_hist, dim3(blocks), dim3(threads), 0, stream,
                       (const float4*)x, out, n);
}

// Round 2
// 923.851 us; speedup vs baseline: 2.0074x; 2.0074x over previous
//
#include <hip/hip_runtime.h>
#include <stdint.h>

// Radix-binning restructure: global fp atomics (fabric-bound, 21 G/s measured)
// -> LDS-only accumulation.
// bucket = dt*600 + p*300 + pos  (4*2*300 = 2400 buckets)
// inner  = tok (256) x channel (2)
// payload u32 = (tok << 24) | round-down fixed-point wt (24 bits)

#define TPB 256
#define B1 1024            // blocks for count/scatter passes
#define NBUCKET 2400
#define PER_SCAN 4         // B1 / TPB elements per thread in k_scan_blocks
#define PER_B 10           // ceil(NBUCKET / TPB) in k_scan_buckets

// ws layout, u32 units
#define OFF_COUNTS 0u
#define OFF_TOTALS ((uint32_t)(NBUCKET * B1))            // 2,457,600
#define OFF_BASES  (OFF_TOTALS + NBUCKET)                // 2,460,000
#define OFF_PAYLOAD (OFF_BASES + NBUCKET)                // 2,462,400

__device__ __forceinline__ void classify(const float4 e, const float t0,
                                         const float d_wt, const float d_dt,
                                         int& bucket, int& tok, float& wt) {
    // exact same fp ops as the round-1 (passing) kernel
    const float c1 = (float)(319.0 / 20.0 + 1e-4);   // W/PW + B
    const float c2 = (float)(239.0 / 15.0 + 1e-4);   // H/PH + B
    const int pos = (int)(floorf(e.y / c1) + floorf(e.z / c2) * 20.0f);
    tok = (int)(floorf(fmodf(e.y, c1)) + floorf(fmodf(e.z, c2)) * 16.0f);
    const int dt = (int)floorf(4.0f * (e.x - t0) / d_dt);
    const int p  = (int)e.w;
    bucket = (dt * 2 + p) * 300 + pos;
    wt = (e.x - t0) / d_wt;
}

__global__ __launch_bounds__(TPB) void k_count(const float4* __restrict__ x,
                                               uint32_t* __restrict__ ws, int n) {
    __shared__ uint32_t cnt[NBUCKET];
    for (int i = threadIdx.x; i < NBUCKET; i += TPB) cnt[i] = 0;
    __syncthreads();
    const float* xf = (const float*)x;
    const float t0 = xf[0];
    const float tlast = xf[(size_t)(n - 1) * 4];
    const float d_wt = tlast - t0 + 1e-4f;
    const float d_dt = tlast - t0 + 1.0f;
    const int chunk = (n + B1 - 1) / B1;
    const int beg = blockIdx.x * chunk;
    const int end = min(beg + chunk, n);
    for (int i = beg + threadIdx.x; i < end; i += TPB) {
        float4 e = x[i];
        int bucket, tok; float wt;
        classify(e, t0, d_wt, d_dt, bucket, tok, wt);
        atomicAdd(&cnt[bucket], 1u);        // LDS atomic
    }
    __syncthreads();
    for (int i = threadIdx.x; i < NBUCKET; i += TPB)
        ws[OFF_COUNTS + (size_t)i * B1 + blockIdx.x] = cnt[i];
}

// One block per bucket: exclusive scan of its B1 per-block counts (in place),
// bucket total -> totals[bucket].
__global__ __launch_bounds__(TPB) void k_scan_blocks(uint32_t* __restrict__ ws) {
    __shared__ uint32_t wsum[TPB / 64];
    uint32_t* row = ws + OFF_COUNTS + (size_t)blockIdx.x * B1;
    uint32_t v[PER_SCAN];
    uint32_t sum = 0;
    const int base_i = threadIdx.x * PER_SCAN;
    #pragma unroll
    for (int j = 0; j < PER_SCAN; ++j) { v[j] = row[base_i + j]; sum += v[j]; }
    // inclusive wave scan of per-thread sums
    uint32_t inc = sum;
    #pragma unroll
    for (int off = 1; off < 64; off <<= 1) {
        uint32_t u = __shfl_up(inc, off, 64);
        if ((threadIdx.x & 63) >= off) inc += u;
    }
    const int wid = threadIdx.x >> 6, lid = threadIdx.x & 63;
    if (lid == 63) wsum[wid] = inc;
    __syncthreads();
    uint32_t woff = 0;
    for (int w = 0; w < wid; ++w) woff += wsum[w];
    uint32_t excl = woff + inc - sum;     // exclusive prefix for this thread's run
    #pragma unroll
    for (int j = 0; j < PER_SCAN; ++j) { row[base_i + j] = excl; excl += v[j]; }
    if (threadIdx.x == TPB - 1) ws[OFF_TOTALS + blockIdx.x] = woff + inc;
}

// Single block: exclusive scan of totals[NBUCKET] -> bases[NBUCKET].
__global__ __launch_bounds__(TPB) void k_scan_buckets(uint32_t* __restrict__ ws) {
    __shared__ uint32_t wsum[TPB / 64];
    const uint32_t* totals = ws + OFF_TOTALS;
    uint32_t* bases = ws + OFF_BASES;
    uint32_t loc[PER_B];
    uint32_t sum = 0;
    const int base_i = threadIdx.x * PER_B;
    #pragma unroll
    for (int j = 0; j < PER_B; ++j) {
        int i = base_i + j;
        uint32_t t = (i < NBUCKET) ? totals[i] : 0;
        loc[j] = sum;
        sum += t;
    }
    uint32_t inc = sum;
    #pragma unroll
    for (int off = 1; off < 64; off <<= 1) {
        uint32_t u = __shfl_up(inc, off, 64);
        if ((threadIdx.x & 63) >= off) inc += u;
    }
    const int wid = threadIdx.x >> 6, lid = threadIdx.x & 63;
    if (lid == 63) wsum[wid] = inc;
    __syncthreads();
    uint32_t woff = 0;
    for (int w = 0; w < wid; ++w) woff += wsum[w];
    const uint32_t texcl = woff + inc - sum;
    #pragma unroll
    for (int j = 0; j < PER_B; ++j) {
        int i = base_i + j;
        if (i < NBUCKET) bases[i] = texcl + loc[j];
    }
}

__global__ __launch_bounds__(TPB) void k_scatter(const float4* __restrict__ x,
                                                 uint32_t* __restrict__ ws, int n) {
    __shared__ uint32_t cursor[NBUCKET];
    const uint32_t* prefix = ws + OFF_COUNTS;
    const uint32_t* bases = ws + OFF_BASES;
    for (int i = threadIdx.x; i < NBUCKET; i += TPB)
        cursor[i] = bases[i] + prefix[(size_t)i * B1 + blockIdx.x];
    __syncthreads();
    const float* xf = (const float*)x;
    const float t0 = xf[0];
    const float tlast = xf[(size_t)(n - 1) * 4];
    const float d_wt = tlast - t0 + 1e-4f;
    const float d_dt = tlast - t0 + 1.0f;
    uint32_t* payload = ws + OFF_PAYLOAD;
    const int chunk = (n + B1 - 1) / B1;
    const int beg = blockIdx.x * chunk;
    const int end = min(beg + chunk, n);
    for (int i = beg + threadIdx.x; i < end; i += TPB) {
        float4 e = x[i];
        int bucket, tok; float wt;
        classify(e, t0, d_wt, d_dt, bucket, tok, wt);
        uint32_t q = (uint32_t)(wt * 16777216.0f);
        q = q > 16777215u ? 16777215u : q;   // wt can round to 1.0f; keep tok bits clean
        uint32_t rank = atomicAdd(&cursor[bucket], 1u);   // LDS atomic, returns old
        payload[rank] = ((uint32_t)tok << 24) | q;
    }
}

// One block per bucket: stream its contiguous payload range into a 512-float
// LDS histogram (tok x {count, wt}), then write 512 outputs exactly once.
__global__ __launch_bounds__(TPB) void k_accum(const uint32_t* __restrict__ ws,
                                               float* __restrict__ out) {
    __shared__ float hist[512];
    hist[threadIdx.x] = 0.0f;
    hist[threadIdx.x + 256] = 0.0f;
    __syncthreads();
    const int b = blockIdx.x;
    const uint32_t beg = ws[OFF_BASES + b];
    const uint32_t cnt = ws[OFF_TOTALS + b];
    const uint32_t* payload = ws + OFF_PAYLOAD;
    for (uint32_t i = threadIdx.x; i < cnt; i += TPB) {
        uint32_t v = payload[beg + i];
        int tok = v >> 24;
        float wt = (float)(v & 0xFFFFFFu) * (1.0f / 16777216.0f);
        atomicAdd(&hist[tok], 1.0f);          // LDS fp atomic (ds_add_f32)
        atomicAdd(&hist[256 + tok], wt);
    }
    __syncthreads();
    // b = (dt*2+p)*300 + pos; out = (dt*2+p)*153600 + c*76800 + tok*300 + pos
    const int pos = b % 300;
    const int dp = b / 300;
    const int base0 = dp * 153600 + pos;
    out[base0 + threadIdx.x * 300]         = hist[threadIdx.x];        // c=0 count
    out[base0 + 76800 + threadIdx.x * 300] = hist[256 + threadIdx.x];  // c=1 wt sum
}

// ---- round-1 fallback (used only if ws_size is too small) ----
__global__ __launch_bounds__(TPB) void e2src_hist_atomic(const float4* __restrict__ x,
                                                         float* __restrict__ out, int n) {
    const float* xf = (const float*)x;
    const float t0 = xf[0];
    const float tlast = xf[(size_t)(n - 1) * 4];
    const float d_wt = tlast - t0 + 1e-4f;
    const float d_dt = tlast - t0 + 1.0f;
    int i = blockIdx.x * blockDim.x + threadIdx.x;
    const int stride = gridDim.x * blockDim.x;
    for (; i < n; i += stride) {
        float4 e = x[i];
        int bucket, tok; float wt;
        classify(e, t0, d_wt, d_dt, bucket, tok, wt);
        const int dp = bucket / 300, pos = bucket % 300;
        const int base = dp * 153600 + tok * 300 + pos;
        unsafeAtomicAdd(out + base, 1.0f);
        unsafeAtomicAdd(out + base + 76800, wt);
    }
}

extern "C" void kernel_launch(void* const* d_in, const int* in_sizes, int n_in,
                              void* d_out, int out_size, void* d_ws, size_t ws_size,
                              hipStream_t stream) {
    const float* x = (const float*)d_in[0];
    float* out = (float*)d_out;
    const int n = in_sizes[0] / 4;

    const size_t need = ((size_t)OFF_PAYLOAD + (size_t)n) * 4u;  // ~77 MB
    if (ws_size < need) {
        hipMemsetAsync(d_out, 0, (size_t)out_size * sizeof(float), stream);
        hipLaunchKernelGGL(e2src_hist_atomic, dim3(8192), dim3(TPB), 0, stream,
                           (const float4*)x, out, n);
        return;
    }

    uint32_t* ws = (uint32_t*)d_ws;
    hipLaunchKernelGGL(k_count,        dim3(B1),      dim3(TPB), 0, stream, (const float4*)x, ws, n);
    hipLaunchKernelGGL(k_scan_blocks,  dim3(NBUCKET), dim3(TPB), 0, stream, ws);
    hipLaunchKernelGGL(k_scan_buckets, dim3(1),       dim3(TPB), 0, stream, ws);
    hipLaunchKernelGGL(k_scatter,      dim3(B1),      dim3(TPB), 0, stream, (const float4*)x, ws, n);
    hipLaunchKernelGGL(k_accum,        dim3(NBUCKET), dim3(TPB), 0, stream, ws, out);
    // k_accum writes all 1,228,800 outputs exactly once -> no memset needed.
}